// Round 1
// baseline (1741.387 us; speedup 1.0000x reference)
//
#include <hip/hip_runtime.h>

#define Bv 4
#define Sv 2048
#define Dv 1024
#define Hv 16
#define HDv 64

// ---------------------------------------------------------------------------
// Kernel 1: Q/K/V projection.  O = X @ W^T + bias, written as [B,H,S,HD].
// Tile 64x64, block 256 threads, each thread owns a 4x4 micro-tile.
// blockIdx.z in {0,1,2} selects (Wq,bq,Q) / (Wk,bk,K) / (Wv,bv,V).
// ---------------------------------------------------------------------------
__global__ __launch_bounds__(256) void qkv_gemm_kernel(
    const float* __restrict__ X,
    const float* __restrict__ Wq, const float* __restrict__ bq,
    const float* __restrict__ Wk, const float* __restrict__ bk,
    const float* __restrict__ Wv, const float* __restrict__ bv,
    float* __restrict__ Q, float* __restrict__ Kp, float* __restrict__ Vp)
{
    const int which = blockIdx.z;
    const float* __restrict__ W    = (which == 0) ? Wq : (which == 1) ? Wk : Wv;
    const float* __restrict__ bias = (which == 0) ? bq : (which == 1) ? bk : bv;
    float* __restrict__ O          = (which == 0) ? Q  : (which == 1) ? Kp : Vp;

    // k-major LDS tiles, padded to 68 floats (272B stride, 16B-aligned rows)
    __shared__ float As[16][68];
    __shared__ float Bs[16][68];

    const int tid = threadIdx.x;
    const int tx = tid & 15, ty = tid >> 4;
    const int m0 = blockIdx.x * 64;
    const int n0 = blockIdx.y * 64;
    const int lr = tid >> 2;           // tile row this thread stages (0..63)
    const int lk = (tid & 3) << 2;     // k offset this thread stages (0,4,8,12)

    float acc[4][4] = {};

    for (int k0 = 0; k0 < Dv; k0 += 16) {
        float4 av = *reinterpret_cast<const float4*>(&X[(size_t)(m0 + lr) * Dv + k0 + lk]);
        float4 wv = *reinterpret_cast<const float4*>(&W[(size_t)(n0 + lr) * Dv + k0 + lk]);
        __syncthreads();  // previous iteration's readers done
        As[lk + 0][lr] = av.x; As[lk + 1][lr] = av.y;
        As[lk + 2][lr] = av.z; As[lk + 3][lr] = av.w;
        Bs[lk + 0][lr] = wv.x; Bs[lk + 1][lr] = wv.y;
        Bs[lk + 2][lr] = wv.z; Bs[lk + 3][lr] = wv.w;
        __syncthreads();
#pragma unroll
        for (int kk = 0; kk < 16; ++kk) {
            float4 a4 = *reinterpret_cast<const float4*>(&As[kk][ty << 2]);
            float4 b4 = *reinterpret_cast<const float4*>(&Bs[kk][tx << 2]);
            float a[4] = {a4.x, a4.y, a4.z, a4.w};
            float b[4] = {b4.x, b4.y, b4.z, b4.w};
#pragma unroll
            for (int i = 0; i < 4; ++i)
#pragma unroll
                for (int j = 0; j < 4; ++j)
                    acc[i][j] = fmaf(a[i], b[j], acc[i][j]);
        }
    }

    // n0 is a multiple of 64 == HD, so the whole tile is one head.
    const int h = n0 >> 6;
#pragma unroll
    for (int i = 0; i < 4; ++i) {
        int m = m0 + (ty << 2) + i;
        int bb = m >> 11;          // m / S
        int s  = m & 2047;         // m % S
#pragma unroll
        for (int j = 0; j < 4; ++j) {
            int d = (tx << 2) + j;
            O[((size_t)((bb * Hv + h) * Sv + s)) * HDv + d] = acc[i][j] + bias[n0 + d];
        }
    }
}

// ---------------------------------------------------------------------------
// Kernel 2: flash attention, fp32.  One workgroup = (b,h) x 64 query rows.
// 256 threads as 16x16; thread (ty,tx) owns score rows ty*4..+3 and
// score cols / ctx dims tx*4..+3.
// ---------------------------------------------------------------------------
__global__ __launch_bounds__(256) void attn_kernel(
    const float* __restrict__ Q,
    const float* __restrict__ K,
    const float* __restrict__ V,
    const float* __restrict__ mask,
    float* __restrict__ out)
{
    const int bh = blockIdx.y;              // b*H + h
    const int bb = bh >> 4, h = bh & 15;
    const int q0 = blockIdx.x * 64;
    const int tid = threadIdx.x;
    const int tx = tid & 15, ty = tid >> 4;

    __shared__ float Qs[HDv][68];   // d-major: Qs[d][row]
    __shared__ float Ks[HDv][68];   // d-major: Ks[d][col]
    __shared__ float Vs[64][68];    // c-major: Vs[col][d]
    __shared__ float Ps[64][68];    // c-major: Ps[col][row]
    __shared__ float Ms[64];        // mask tile

    const float* __restrict__ Qb = Q + (size_t)bh * Sv * HDv;
    const float* __restrict__ Kb = K + (size_t)bh * Sv * HDv;
    const float* __restrict__ Vb = V + (size_t)bh * Sv * HDv;
    const float* __restrict__ mb = mask + (size_t)bb * Sv;

    // stage the Q tile (64 rows x 64 dims), transposed to d-major
    {
        int r = tid >> 2, d0 = (tid & 3) << 4;
#pragma unroll
        for (int u = 0; u < 16; u += 4) {
            float4 v = *reinterpret_cast<const float4*>(&Qb[(size_t)(q0 + r) * HDv + d0 + u]);
            Qs[d0 + u + 0][r] = v.x; Qs[d0 + u + 1][r] = v.y;
            Qs[d0 + u + 2][r] = v.z; Qs[d0 + u + 3][r] = v.w;
        }
    }

    float ctx[4][4] = {};
    float mrow[4], lrow[4];
#pragma unroll
    for (int i = 0; i < 4; ++i) { mrow[i] = -1e30f; lrow[i] = 0.f; }

    for (int k0 = 0; k0 < Sv; k0 += 64) {
        // ---- stage K (d-major) and V (c-major) tiles ----
        {
            int c = tid >> 2, d0 = (tid & 3) << 4;
            __syncthreads();   // previous iteration's consumers done
#pragma unroll
            for (int u = 0; u < 16; u += 4) {
                float4 kv = *reinterpret_cast<const float4*>(&Kb[(size_t)(k0 + c) * HDv + d0 + u]);
                Ks[d0 + u + 0][c] = kv.x; Ks[d0 + u + 1][c] = kv.y;
                Ks[d0 + u + 2][c] = kv.z; Ks[d0 + u + 3][c] = kv.w;
                float4 vv = *reinterpret_cast<const float4*>(&Vb[(size_t)(k0 + c) * HDv + d0 + u]);
                *reinterpret_cast<float4*>(&Vs[c][d0 + u]) = vv;
            }
            if (tid < 64) Ms[tid] = mb[k0 + tid];
            __syncthreads();
        }

        // ---- S-tile: sc[i][j] = Q[r_i] . K[c_j] ----
        float sc[4][4] = {};
#pragma unroll 8
        for (int d = 0; d < HDv; ++d) {
            float4 a4 = *reinterpret_cast<const float4*>(&Qs[d][ty << 2]);
            float4 b4 = *reinterpret_cast<const float4*>(&Ks[d][tx << 2]);
            float a[4] = {a4.x, a4.y, a4.z, a4.w};
            float b[4] = {b4.x, b4.y, b4.z, b4.w};
#pragma unroll
            for (int i = 0; i < 4; ++i)
#pragma unroll
                for (int j = 0; j < 4; ++j)
                    sc[i][j] = fmaf(a[i], b[j], sc[i][j]);
        }

        // ---- scale + mask + row max ----
        float tmax[4] = {-1e30f, -1e30f, -1e30f, -1e30f};
#pragma unroll
        for (int i = 0; i < 4; ++i)
#pragma unroll
            for (int j = 0; j < 4; ++j) {
                float mk = Ms[(tx << 2) + j];
                float s = sc[i][j] * 0.125f;          // 1/sqrt(64)
                s = (mk >= 0.f) ? s + mk : mk;        // custom mask semantics
                sc[i][j] = s;
                tmax[i] = fmaxf(tmax[i], s);
            }
        // reduce max across the 16 lanes sharing a row (lanes ty*16..+15)
#pragma unroll
        for (int i = 0; i < 4; ++i) {
            float v = tmax[i];
            for (int off = 1; off < 16; off <<= 1) v = fmaxf(v, __shfl_xor(v, off));
            tmax[i] = v;
        }

        // ---- online softmax update ----
        float pscale[4];
#pragma unroll
        for (int i = 0; i < 4; ++i) {
            float mnew = fmaxf(mrow[i], tmax[i]);
            pscale[i] = __expf(mrow[i] - mnew);       // 0 on first iter
            mrow[i] = mnew;
        }
        float tsum[4] = {0.f, 0.f, 0.f, 0.f};
#pragma unroll
        for (int i = 0; i < 4; ++i)
#pragma unroll
            for (int j = 0; j < 4; ++j) {
                float p = __expf(sc[i][j] - mrow[i]);
                sc[i][j] = p;
                tsum[i] += p;
            }
#pragma unroll
        for (int i = 0; i < 4; ++i) {
            float v = tsum[i];
            for (int off = 1; off < 16; off <<= 1) v += __shfl_xor(v, off);
            lrow[i] = lrow[i] * pscale[i] + v;
        }
#pragma unroll
        for (int i = 0; i < 4; ++i)
#pragma unroll
            for (int j = 0; j < 4; ++j) ctx[i][j] *= pscale[i];

        // ---- write P tile (c-major) and do PV ----
        // Safe to overwrite Ps: all threads passed the staging barriers above,
        // so last iteration's PV reads are complete.
#pragma unroll
        for (int i = 0; i < 4; ++i)
#pragma unroll
            for (int j = 0; j < 4; ++j)
                Ps[(tx << 2) + j][(ty << 2) + i] = sc[i][j];
        __syncthreads();

#pragma unroll 8
        for (int c = 0; c < 64; ++c) {
            float4 p4 = *reinterpret_cast<const float4*>(&Ps[c][ty << 2]);
            float4 v4 = *reinterpret_cast<const float4*>(&Vs[c][tx << 2]);
            float p[4] = {p4.x, p4.y, p4.z, p4.w};
            float v[4] = {v4.x, v4.y, v4.z, v4.w};
#pragma unroll
            for (int i = 0; i < 4; ++i)
#pragma unroll
                for (int j = 0; j < 4; ++j)
                    ctx[i][j] = fmaf(p[i], v[j], ctx[i][j]);
        }
    }

    // ---- finalize: divide by l, write [B,S,D] ----
#pragma unroll
    for (int i = 0; i < 4; ++i) {
        int s = q0 + (ty << 2) + i;
        float inv = 1.0f / lrow[i];
#pragma unroll
        for (int j = 0; j < 4; ++j) {
            out[((size_t)(bb * Sv + s)) * Dv + h * HDv + (tx << 2) + j] = ctx[i][j] * inv;
        }
    }
}

extern "C" void kernel_launch(void* const* d_in, const int* in_sizes, int n_in,
                              void* d_out, int out_size, void* d_ws, size_t ws_size,
                              hipStream_t stream) {
    const float* X    = (const float*)d_in[0];
    const float* mask = (const float*)d_in[1];
    const float* Wq   = (const float*)d_in[2];
    const float* bq   = (const float*)d_in[3];
    const float* Wk   = (const float*)d_in[4];
    const float* bk   = (const float*)d_in[5];
    const float* Wv   = (const float*)d_in[6];
    const float* bv   = (const float*)d_in[7];
    float* out = (float*)d_out;

    float* ws = (float*)d_ws;
    const size_t per = (size_t)Bv * Sv * Dv;   // 8388608 floats = 32 MB
    float* Q = ws;
    float* K = ws + per;
    float* V = ws + 2 * per;

    // QKV projections: M=8192 rows, N=1024 cols, z selects Q/K/V
    qkv_gemm_kernel<<<dim3((Bv * Sv) / 64, Dv / 64, 3), 256, 0, stream>>>(
        X, Wq, bq, Wk, bk, Wv, bv, Q, K, V);

    // Flash attention: 32 q-tiles x 64 (b,h) pairs
    attn_kernel<<<dim3(Sv / 64, Bv * Hv), 256, 0, stream>>>(Q, K, V, mask, out);
}

// Round 2
// 226.068 us; speedup vs baseline: 7.7029x; 7.7029x over previous
//
#include <hip/hip_runtime.h>

typedef __attribute__((ext_vector_type(8)))  short short8;
typedef __attribute__((ext_vector_type(4)))  float f32x4;
typedef __attribute__((ext_vector_type(16))) float f32x16;

#define Bv 4
#define Sv 2048
#define Dv 1024
#define Hv 16
#define HDv 64

// workspace byte offsets
#define OFF_XB  (size_t)0           // X bf16      [8192][1024]  16MB
#define OFF_WC  (size_t)16777216    // Wcat bf16   [3072][1024]   6MB
#define OFF_QB  (size_t)25165824    // Q bf16  [64][2048][64]    16MB
#define OFF_KB  (size_t)41943040    // K bf16  [64][2048][64]    16MB
#define OFF_VB  (size_t)58720256    // V bf16  [64][2048][64]    16MB
#define OFF_VT  (size_t)75497472    // V^T bf16 [64][64][2048]   16MB

__device__ __forceinline__ unsigned short f2bf(float f) {
    union { float f; unsigned u; } v; v.f = f;
    unsigned r = v.u + 0x7FFFu + ((v.u >> 16) & 1u);   // RNE
    return (unsigned short)(r >> 16);
}
__device__ __forceinline__ unsigned packbf(float a, float b) {
    return (unsigned)f2bf(a) | ((unsigned)f2bf(b) << 16);
}
__device__ __forceinline__ float f4get(const float4& v, int i) {
    return i == 0 ? v.x : i == 1 ? v.y : i == 2 ? v.z : v.w;
}

#define GLOAD16(gp, lp)                                                        \
    __builtin_amdgcn_global_load_lds(                                          \
        (const __attribute__((address_space(1))) void*)(gp),                   \
        (__attribute__((address_space(3))) void*)(lp), 16, 0, 0)

// ---------------------------------------------------------------------------
// fp32 -> bf16 convert: X (8.4M) and Wq|Wk|Wv -> Wcat (3.1M)
// ---------------------------------------------------------------------------
__global__ void convert_kernel(const float* __restrict__ X,
                               const float* __restrict__ Wq,
                               const float* __restrict__ Wk,
                               const float* __restrict__ Wv,
                               unsigned short* __restrict__ Xb,
                               unsigned short* __restrict__ Wc) {
    size_t i = ((size_t)blockIdx.x * 256 + threadIdx.x) * 4;
    if (i < 8388608) {
        float4 v = *(const float4*)(X + i);
        ushort4 o; o.x = f2bf(v.x); o.y = f2bf(v.y); o.z = f2bf(v.z); o.w = f2bf(v.w);
        *(ushort4*)(Xb + i) = o;
    } else {
        size_t j = i - 8388608;
        int which = (int)(j >> 20);
        size_t r = j & 1048575;
        const float* W = which == 0 ? Wq : which == 1 ? Wk : Wv;
        float4 v = *(const float4*)(W + r);
        ushort4 o; o.x = f2bf(v.x); o.y = f2bf(v.y); o.z = f2bf(v.z); o.w = f2bf(v.w);
        *(ushort4*)(Wc + j) = o;
    }
}

// ---------------------------------------------------------------------------
// QKV projection GEMM: [8192 x 1024] x [3072 x 1024]^T + bias -> bf16
// 128x128 tile, BK=64, 4 waves, 16x16x32 MFMA, global_load_lds + XOR swizzle.
// Output written as [b,h,s,d] per head.
// ---------------------------------------------------------------------------
__global__ void qkv_gemm(const unsigned short* __restrict__ Xb,
                         const unsigned short* __restrict__ Wc,
                         const float* __restrict__ bq,
                         const float* __restrict__ bk,
                         const float* __restrict__ bv,
                         unsigned short* __restrict__ Qb,
                         unsigned short* __restrict__ Kb,
                         unsigned short* __restrict__ Vb) {
    __shared__ __align__(16) char sm[32768];
    char* As = sm;
    char* Bs = sm + 16384;

    const int tid  = threadIdx.x;
    const int w    = tid >> 6, lane = tid & 63;
    const int l15  = lane & 15, g = lane >> 4;
    const int m0   = blockIdx.x * 128, n0 = blockIdx.y * 128;
    const int wr   = (w >> 1) * 64, wc = (w & 1) * 64;
    const int srow = (lane >> 3);    // staging sub-row
    const int slot = lane & 7;

    f32x4 acc[4][4];
#pragma unroll
    for (int a = 0; a < 4; ++a)
#pragma unroll
        for (int b = 0; b < 4; ++b)
#pragma unroll
            for (int r = 0; r < 4; ++r) acc[a][b][r] = 0.f;

    for (int k0 = 0; k0 < 1024; k0 += 64) {
        __syncthreads();   // previous iteration's readers done
#pragma unroll
        for (int i = 0; i < 4; ++i) {
            int row = w * 32 + i * 8 + srow;
            int koff = (slot ^ (row & 7)) << 3;
            const unsigned short* ga = Xb + (size_t)(m0 + row) * 1024 + k0 + koff;
            GLOAD16(ga, As + w * 4096 + i * 1024);
            const unsigned short* gb = Wc + (size_t)(n0 + row) * 1024 + k0 + koff;
            GLOAD16(gb, Bs + w * 4096 + i * 1024);
        }
        __syncthreads();   // drains vmcnt: staged tile visible
#pragma unroll
        for (int ks = 0; ks < 2; ++ks) {
            short8 af[4], bf[4];
#pragma unroll
            for (int fm = 0; fm < 4; ++fm) {
                int row = wr + fm * 16 + l15;
                int sl = (g + 4 * ks) ^ (row & 7);
                af[fm] = *(const short8*)(As + row * 128 + sl * 16);
            }
#pragma unroll
            for (int fn = 0; fn < 4; ++fn) {
                int row = wc + fn * 16 + l15;
                int sl = (g + 4 * ks) ^ (row & 7);
                bf[fn] = *(const short8*)(Bs + row * 128 + sl * 16);
            }
#pragma unroll
            for (int fm = 0; fm < 4; ++fm)
#pragma unroll
                for (int fn = 0; fn < 4; ++fn)
                    acc[fm][fn] = __builtin_amdgcn_mfma_f32_16x16x32_bf16(
                        af[fm], bf[fn], acc[fm][fn], 0, 0, 0);
        }
    }

    // epilogue: bias + bf16 + scatter into [b,h,s,d]
#pragma unroll
    for (int fn = 0; fn < 4; ++fn) {
        int ng = n0 + wc + fn * 16 + l15;
        int which = ng >> 10, nn = ng & 1023;
        const float* bias = which == 0 ? bq : which == 1 ? bk : bv;
        unsigned short* Out = which == 0 ? Qb : which == 1 ? Kb : Vb;
        float bvv = bias[nn];
        int h = nn >> 6, d = nn & 63;
#pragma unroll
        for (int fm = 0; fm < 4; ++fm) {
#pragma unroll
            for (int r = 0; r < 4; ++r) {
                int m = m0 + wr + fm * 16 + 4 * g + r;
                int b = m >> 11, s = m & 2047;
                Out[(size_t)((b * 16 + h) * 2048 + s) * 64 + d] = f2bf(acc[fm][fn][r] + bvv);
            }
        }
    }
}

// ---------------------------------------------------------------------------
// V [bh][s][d] -> V^T [bh][d][s]
// ---------------------------------------------------------------------------
__global__ void transpose_v(const unsigned short* __restrict__ Vb,
                            unsigned short* __restrict__ Vt) {
    __shared__ unsigned short lds[64][72];
    const int bh = blockIdx.y, s0 = blockIdx.x * 64;
    const int tid = threadIdx.x;
    {
        int r = tid >> 2, c0 = (tid & 3) * 16;
        const unsigned short* src = Vb + (size_t)(bh * 2048 + s0 + r) * 64 + c0;
        *(short8*)&lds[r][c0]     = *(const short8*)(src);
        *(short8*)&lds[r][c0 + 8] = *(const short8*)(src + 8);
    }
    __syncthreads();
    {
        int d = tid >> 2, c0 = (tid & 3) * 16;
        union { unsigned short u[16]; short8 s[2]; } tb;
#pragma unroll
        for (int j = 0; j < 16; ++j) tb.u[j] = lds[c0 + j][d];
        unsigned short* dst = Vt + (size_t)(bh * 64 + d) * 2048 + s0 + c0;
        *(short8*)(dst)     = tb.s[0];
        *(short8*)(dst + 8) = tb.s[1];
    }
}

// ---------------------------------------------------------------------------
// Flash attention, 32x32x16 bf16 MFMA, swapped (S^T / O^T) orientation.
// Block: 4 waves x 64 q-rows = 256-row q-tile. kv tiles of 64, double-buffered.
// ---------------------------------------------------------------------------
__device__ __forceinline__ void attn_stage(char* sm, int buf, int kv0,
                                           const unsigned short* Kg,
                                           const unsigned short* Vt,
                                           int bh, int w, int lane) {
    char* Kb = sm + buf * 16384;
    char* Vb = Kb + 8192;
    const int srow = lane >> 3, slot = lane & 7;
#pragma unroll
    for (int i = 0; i < 2; ++i) {
        int row = w * 16 + i * 8 + srow;
        int koff = (slot ^ (row & 7)) << 3;
        const unsigned short* gk = Kg + (size_t)(bh * 2048 + kv0 + row) * 64 + koff;
        GLOAD16(gk, Kb + w * 2048 + i * 1024);
        const unsigned short* gv = Vt + (size_t)(bh * 64 + row) * 2048 + kv0 + koff;
        GLOAD16(gv, Vb + w * 2048 + i * 1024);
    }
}

__global__ __launch_bounds__(256, 2) void attn_kernel(
    const unsigned short* __restrict__ Qg,
    const unsigned short* __restrict__ Kg,
    const unsigned short* __restrict__ Vt,
    const float* __restrict__ mask,
    float* __restrict__ out) {
    __shared__ __align__(16) char sm[32768];
    const int tid = threadIdx.x;
    const int w = tid >> 6, lane = tid & 63;
    const int q31 = lane & 31, g2 = lane >> 5;
    const int bh = blockIdx.y, bb = bh >> 4, h = bh & 15;
    const int q0 = blockIdx.x * 256 + w * 64;
    const float* mrow = mask + bb * 2048;

    // Q fragments, hoisted (B-operand of S^T): qf[qn][ks]
    short8 qf[2][4];
#pragma unroll
    for (int qn = 0; qn < 2; ++qn)
#pragma unroll
        for (int ks = 0; ks < 4; ++ks)
            qf[qn][ks] = *(const short8*)(Qg + (size_t)(bh * 2048 + q0 + qn * 32 + q31) * 64
                                          + ks * 16 + g2 * 8);

    f32x16 o[2][2];
#pragma unroll
    for (int dm = 0; dm < 2; ++dm)
#pragma unroll
        for (int qn = 0; qn < 2; ++qn)
#pragma unroll
            for (int r = 0; r < 16; ++r) o[dm][qn][r] = 0.f;
    float mN[2] = {-3e38f, -3e38f}, lN[2] = {0.f, 0.f};

    attn_stage(sm, 0, 0, Kg, Vt, bh, w, lane);
    __syncthreads();

    for (int t = 0; t < 32; ++t) {
        const int kv0 = t * 64;
        const char* Kb = sm + (t & 1) * 16384;
        const char* Vb = Kb + 8192;
        if (t + 1 < 32) attn_stage(sm, (t + 1) & 1, kv0 + 64, Kg, Vt, bh, w, lane);

        // mask vectors: mkv[cm][rq] covers c = kv0 + 32cm + 8rq + 4g2 + [0..3]
        float4 mkv[2][4];
#pragma unroll
        for (int cm = 0; cm < 2; ++cm)
#pragma unroll
            for (int rq = 0; rq < 4; ++rq)
                mkv[cm][rq] = *(const float4*)(mrow + kv0 + cm * 32 + rq * 8 + g2 * 4);

        // S^T = K * Q^T
        f32x16 st[2][2];
#pragma unroll
        for (int cm = 0; cm < 2; ++cm)
#pragma unroll
            for (int qn = 0; qn < 2; ++qn)
#pragma unroll
                for (int r = 0; r < 16; ++r) st[cm][qn][r] = 0.f;
#pragma unroll
        for (int ks = 0; ks < 4; ++ks) {
#pragma unroll
            for (int cm = 0; cm < 2; ++cm) {
                int row = cm * 32 + q31;
                int sl = (2 * ks + g2) ^ (row & 7);
                short8 kf = *(const short8*)(Kb + row * 128 + sl * 16);
#pragma unroll
                for (int qn = 0; qn < 2; ++qn)
                    st[cm][qn] = __builtin_amdgcn_mfma_f32_32x32x16_bf16(
                        kf, qf[qn][ks], st[cm][qn], 0, 0, 0);
            }
        }

        // V^T fragments (A-operand of O^T): vf[dm][ks]
        short8 vf[2][4];
#pragma unroll
        for (int ks = 0; ks < 4; ++ks)
#pragma unroll
            for (int dm = 0; dm < 2; ++dm) {
                int row = dm * 32 + q31;
                int sl = (2 * ks + g2) ^ (row & 7);
                vf[dm][ks] = *(const short8*)(Vb + row * 128 + sl * 16);
            }

#pragma unroll
        for (int qn = 0; qn < 2; ++qn) {
            // scale + mask + row max  (c = kv0 + 32cm + (r&3) + 8(r>>2) + 4g2)
            float tm = -3e38f;
#pragma unroll
            for (int cm = 0; cm < 2; ++cm)
#pragma unroll
                for (int r = 0; r < 16; ++r) {
                    float mk = f4get(mkv[cm][r >> 2], r & 3);
                    float sv = st[cm][qn][r] * 0.125f;
                    sv = (mk >= 0.f) ? sv + mk : mk;
                    st[cm][qn][r] = sv;
                    tm = fmaxf(tm, sv);
                }
            tm = fmaxf(tm, __shfl_xor(tm, 32));
            float mnew = fmaxf(mN[qn], tm);
            float ps = __expf(mN[qn] - mnew);
            mN[qn] = mnew;
            float ts = 0.f;
#pragma unroll
            for (int cm = 0; cm < 2; ++cm)
#pragma unroll
                for (int r = 0; r < 16; ++r) {
                    float p = __expf(st[cm][qn][r] - mnew);
                    st[cm][qn][r] = p;
                    ts += p;
                }
            ts += __shfl_xor(ts, 32);
            lN[qn] = lN[qn] * ps + ts;
#pragma unroll
            for (int dm = 0; dm < 2; ++dm)
#pragma unroll
                for (int r = 0; r < 16; ++r) o[dm][qn][r] *= ps;

            // PV: O^T += V^T * P^T ; build P^T B-frag via half-swap
#pragma unroll
            for (int ks = 0; ks < 4; ++ks) {
                const int cm = ks >> 1;
                const int b0 = 8 * (ks & 1);
                unsigned x0 = packbf(st[cm][qn][b0 + 0], st[cm][qn][b0 + 1]);
                unsigned x1 = packbf(st[cm][qn][b0 + 2], st[cm][qn][b0 + 3]);
                unsigned y0 = packbf(st[cm][qn][b0 + 4], st[cm][qn][b0 + 5]);
                unsigned y1 = packbf(st[cm][qn][b0 + 6], st[cm][qn][b0 + 7]);
                unsigned xr0 = (unsigned)__shfl_xor((int)x0, 32);
                unsigned xr1 = (unsigned)__shfl_xor((int)x1, 32);
                unsigned yr0 = (unsigned)__shfl_xor((int)y0, 32);
                unsigned yr1 = (unsigned)__shfl_xor((int)y1, 32);
                union { unsigned u[4]; short8 s; } pb;
                pb.u[0] = g2 ? yr0 : x0;
                pb.u[1] = g2 ? yr1 : x1;
                pb.u[2] = g2 ? y0 : xr0;
                pb.u[3] = g2 ? y1 : xr1;
#pragma unroll
                for (int dm = 0; dm < 2; ++dm)
                    o[dm][qn] = __builtin_amdgcn_mfma_f32_32x32x16_bf16(
                        vf[dm][ks], pb.s, o[dm][qn], 0, 0, 0);
            }
        }
        __syncthreads();   // next tile staged + this tile's LDS reads done
    }

    // epilogue: divide by l, write fp32 [B,S,D]
#pragma unroll
    for (int qn = 0; qn < 2; ++qn) {
        float inv = 1.f / lN[qn];
        int s = q0 + qn * 32 + q31;
#pragma unroll
        for (int dm = 0; dm < 2; ++dm)
#pragma unroll
            for (int rq = 0; rq < 4; ++rq) {
                float4 v;
                v.x = o[dm][qn][rq * 4 + 0] * inv;
                v.y = o[dm][qn][rq * 4 + 1] * inv;
                v.z = o[dm][qn][rq * 4 + 2] * inv;
                v.w = o[dm][qn][rq * 4 + 3] * inv;
                int d = dm * 32 + rq * 8 + g2 * 4;
                *(float4*)(out + (size_t)(bb * 2048 + s) * 1024 + h * 64 + d) = v;
            }
    }
}

extern "C" void kernel_launch(void* const* d_in, const int* in_sizes, int n_in,
                              void* d_out, int out_size, void* d_ws, size_t ws_size,
                              hipStream_t stream) {
    const float* X    = (const float*)d_in[0];
    const float* mask = (const float*)d_in[1];
    const float* Wq   = (const float*)d_in[2];
    const float* bq   = (const float*)d_in[3];
    const float* Wk   = (const float*)d_in[4];
    const float* bk   = (const float*)d_in[5];
    const float* Wv   = (const float*)d_in[6];
    const float* bv   = (const float*)d_in[7];
    float* out = (float*)d_out;

    char* ws = (char*)d_ws;
    unsigned short* Xb = (unsigned short*)(ws + OFF_XB);
    unsigned short* Wc = (unsigned short*)(ws + OFF_WC);
    unsigned short* Qb = (unsigned short*)(ws + OFF_QB);
    unsigned short* Kb = (unsigned short*)(ws + OFF_KB);
    unsigned short* Vb = (unsigned short*)(ws + OFF_VB);
    unsigned short* Vt = (unsigned short*)(ws + OFF_VT);

    convert_kernel<<<11264, 256, 0, stream>>>(X, Wq, Wk, Wv, Xb, Wc);
    qkv_gemm<<<dim3(64, 24), 256, 0, stream>>>(Xb, Wc, bq, bk, bv, Qb, Kb, Vb);
    transpose_v<<<dim3(32, 64), 256, 0, stream>>>(Vb, Vt);
    attn_kernel<<<dim3(8, 64), 256, 0, stream>>>(Qb, Kb, Vt, mask, out);
}

// Round 3
// 212.441 us; speedup vs baseline: 8.1970x; 1.0641x over previous
//
#include <hip/hip_runtime.h>

typedef __attribute__((ext_vector_type(8)))  short short8;
typedef __attribute__((ext_vector_type(4)))  float f32x4;
typedef __attribute__((ext_vector_type(16))) float f32x16;

#define Bv 4
#define Sv 2048
#define Dv 1024
#define Hv 16
#define HDv 64

// workspace byte offsets
#define OFF_XB  (size_t)0           // X bf16      [8192][1024]  16MB
#define OFF_WC  (size_t)16777216    // Wcat bf16   [3072][1024]   6MB
#define OFF_M2  (size_t)23068672    // mask*log2e  [4][2048]     32KB (in the Wc..Qb hole)
#define OFF_QB  (size_t)25165824    // Q bf16  [64][2048][64]    16MB (scaled by 0.125*log2e)
#define OFF_KB  (size_t)41943040    // K bf16  [64][2048][64]    16MB
#define OFF_VB  (size_t)58720256    // V bf16  [64][2048][64]    16MB
#define OFF_VT  (size_t)75497472    // V^T bf16 [64][64][2048]   16MB

#define QSCALE 0.180336879f   /* 0.125 * log2(e) */
#define LOG2E  1.44269504f

__device__ __forceinline__ unsigned short f2bf(float f) {
    union { float f; unsigned u; } v; v.f = f;
    unsigned r = v.u + 0x7FFFu + ((v.u >> 16) & 1u);   // RNE
    return (unsigned short)(r >> 16);
}
__device__ __forceinline__ float f4get(const float4& v, int i) {
    return i == 0 ? v.x : i == 1 ? v.y : i == 2 ? v.z : v.w;
}

#define GLOAD16(gp, lp)                                                        \
    __builtin_amdgcn_global_load_lds(                                          \
        (const __attribute__((address_space(1))) void*)(gp),                   \
        (__attribute__((address_space(3))) void*)(lp), 16, 0, 0)

// ---------------------------------------------------------------------------
// fp32 -> bf16 convert: X, Wq|Wk|Wv -> Wcat; mask -> mask*log2e (fp32)
// ---------------------------------------------------------------------------
__global__ void convert_kernel(const float* __restrict__ X,
                               const float* __restrict__ Wq,
                               const float* __restrict__ Wk,
                               const float* __restrict__ Wv,
                               const float* __restrict__ mask,
                               unsigned short* __restrict__ Xb,
                               unsigned short* __restrict__ Wc,
                               float* __restrict__ M2) {
    size_t i = ((size_t)blockIdx.x * 256 + threadIdx.x) * 4;
    if (i < 8388608) {
        float4 v = *(const float4*)(X + i);
        ushort4 o; o.x = f2bf(v.x); o.y = f2bf(v.y); o.z = f2bf(v.z); o.w = f2bf(v.w);
        *(ushort4*)(Xb + i) = o;
    } else if (i < 11534336) {
        size_t j = i - 8388608;
        int which = (int)(j >> 20);
        size_t r = j & 1048575;
        const float* W = which == 0 ? Wq : which == 1 ? Wk : Wv;
        float4 v = *(const float4*)(W + r);
        ushort4 o; o.x = f2bf(v.x); o.y = f2bf(v.y); o.z = f2bf(v.z); o.w = f2bf(v.w);
        *(ushort4*)(Wc + j) = o;
    } else {
        size_t j = i - 11534336;   // 8192 mask floats
        float4 v = *(const float4*)(mask + j);
        v.x *= LOG2E; v.y *= LOG2E; v.z *= LOG2E; v.w *= LOG2E;
        *(float4*)(M2 + j) = v;
    }
}

// ---------------------------------------------------------------------------
// QKV projection GEMM: [8192 x 1024] x [3072 x 1024]^T + bias -> bf16
// Q output additionally scaled by 0.125*log2(e).
// ---------------------------------------------------------------------------
__global__ void qkv_gemm(const unsigned short* __restrict__ Xb,
                         const unsigned short* __restrict__ Wc,
                         const float* __restrict__ bq,
                         const float* __restrict__ bk,
                         const float* __restrict__ bv,
                         unsigned short* __restrict__ Qb,
                         unsigned short* __restrict__ Kb,
                         unsigned short* __restrict__ Vb) {
    __shared__ __align__(16) char sm[32768];
    char* As = sm;
    char* Bs = sm + 16384;

    const int tid  = threadIdx.x;
    const int w    = tid >> 6, lane = tid & 63;
    const int l15  = lane & 15, g = lane >> 4;
    const int m0   = blockIdx.x * 128, n0 = blockIdx.y * 128;
    const int wr   = (w >> 1) * 64, wc = (w & 1) * 64;
    const int srow = (lane >> 3);
    const int slot = lane & 7;

    f32x4 acc[4][4];
#pragma unroll
    for (int a = 0; a < 4; ++a)
#pragma unroll
        for (int b = 0; b < 4; ++b)
#pragma unroll
            for (int r = 0; r < 4; ++r) acc[a][b][r] = 0.f;

    for (int k0 = 0; k0 < 1024; k0 += 64) {
        __syncthreads();
#pragma unroll
        for (int i = 0; i < 4; ++i) {
            int row = w * 32 + i * 8 + srow;
            int koff = (slot ^ (row & 7)) << 3;
            const unsigned short* ga = Xb + (size_t)(m0 + row) * 1024 + k0 + koff;
            GLOAD16(ga, As + w * 4096 + i * 1024);
            const unsigned short* gb = Wc + (size_t)(n0 + row) * 1024 + k0 + koff;
            GLOAD16(gb, Bs + w * 4096 + i * 1024);
        }
        __syncthreads();
#pragma unroll
        for (int ks = 0; ks < 2; ++ks) {
            short8 af[4], bf[4];
#pragma unroll
            for (int fm = 0; fm < 4; ++fm) {
                int row = wr + fm * 16 + l15;
                int sl = (g + 4 * ks) ^ (row & 7);
                af[fm] = *(const short8*)(As + row * 128 + sl * 16);
            }
#pragma unroll
            for (int fn = 0; fn < 4; ++fn) {
                int row = wc + fn * 16 + l15;
                int sl = (g + 4 * ks) ^ (row & 7);
                bf[fn] = *(const short8*)(Bs + row * 128 + sl * 16);
            }
#pragma unroll
            for (int fm = 0; fm < 4; ++fm)
#pragma unroll
                for (int fn = 0; fn < 4; ++fn)
                    acc[fm][fn] = __builtin_amdgcn_mfma_f32_16x16x32_bf16(
                        af[fm], bf[fn], acc[fm][fn], 0, 0, 0);
        }
    }

#pragma unroll
    for (int fn = 0; fn < 4; ++fn) {
        int ng = n0 + wc + fn * 16 + l15;
        int which = ng >> 10, nn = ng & 1023;
        const float* bias = which == 0 ? bq : which == 1 ? bk : bv;
        unsigned short* Out = which == 0 ? Qb : which == 1 ? Kb : Vb;
        float osc = (which == 0) ? QSCALE : 1.0f;
        float bvv = bias[nn];
        int h = nn >> 6, d = nn & 63;
#pragma unroll
        for (int fm = 0; fm < 4; ++fm) {
#pragma unroll
            for (int r = 0; r < 4; ++r) {
                int m = m0 + wr + fm * 16 + 4 * g + r;
                int b = m >> 11, s = m & 2047;
                Out[(size_t)((b * 16 + h) * 2048 + s) * 64 + d] =
                    f2bf((acc[fm][fn][r] + bvv) * osc);
            }
        }
    }
}

// ---------------------------------------------------------------------------
// V [bh][s][d] -> V^T [bh][d][s]
// ---------------------------------------------------------------------------
__global__ void transpose_v(const unsigned short* __restrict__ Vb,
                            unsigned short* __restrict__ Vt) {
    __shared__ unsigned short lds[64][72];
    const int bh = blockIdx.y, s0 = blockIdx.x * 64;
    const int tid = threadIdx.x;
    {
        int r = tid >> 2, c0 = (tid & 3) * 16;
        const unsigned short* src = Vb + (size_t)(bh * 2048 + s0 + r) * 64 + c0;
        *(short8*)&lds[r][c0]     = *(const short8*)(src);
        *(short8*)&lds[r][c0 + 8] = *(const short8*)(src + 8);
    }
    __syncthreads();
    {
        int d = tid >> 2, c0 = (tid & 3) * 16;
        union { unsigned short u[16]; short8 s[2]; } tb;
#pragma unroll
        for (int j = 0; j < 16; ++j) tb.u[j] = lds[c0 + j][d];
        unsigned short* dst = Vt + (size_t)(bh * 64 + d) * 2048 + s0 + c0;
        *(short8*)(dst)     = tb.s[0];
        *(short8*)(dst + 8) = tb.s[1];
    }
}

// ---------------------------------------------------------------------------
// Flash attention: 4 waves x 32 q-rows = 128-row q-tile, kv tiles of 64,
// double-buffered LDS, swapped (S^T/O^T) MFMA orientation, exp2-domain
// softmax, cvt_pk+permlane32_swap P packing, defer-max rescale.
// ---------------------------------------------------------------------------
__device__ __forceinline__ void attn_stage(char* sm, int buf, int kv0,
                                           const unsigned short* Kg,
                                           const unsigned short* Vt,
                                           int bh, int w, int lane) {
    char* Kb = sm + buf * 16384;
    char* Vb = Kb + 8192;
    const int srow = lane >> 3, slot = lane & 7;
#pragma unroll
    for (int i = 0; i < 2; ++i) {
        int row = w * 16 + i * 8 + srow;
        int koff = (slot ^ (row & 7)) << 3;
        const unsigned short* gk = Kg + (size_t)(bh * 2048 + kv0 + row) * 64 + koff;
        GLOAD16(gk, Kb + w * 2048 + i * 1024);
        const unsigned short* gv = Vt + (size_t)(bh * 64 + row) * 2048 + kv0 + koff;
        GLOAD16(gv, Vb + w * 2048 + i * 1024);
    }
}

__global__ __launch_bounds__(256, 3) void attn_kernel(
    const unsigned short* __restrict__ Qg,
    const unsigned short* __restrict__ Kg,
    const unsigned short* __restrict__ Vt,
    const float* __restrict__ M2,
    float* __restrict__ out) {
    __shared__ __align__(16) char sm[32768];
    const int tid = threadIdx.x;
    const int w = tid >> 6, lane = tid & 63;
    const int q31 = lane & 31, g2 = lane >> 5;
    const int bh = blockIdx.y, bb = bh >> 4, h = bh & 15;
    const int q = blockIdx.x * 128 + w * 32 + q31;   // this lane's query row
    const float* mrow = M2 + bb * 2048;

    // Q fragments (B-operand of S^T), already scaled by 0.125*log2e
    short8 qf[4];
#pragma unroll
    for (int ks = 0; ks < 4; ++ks)
        qf[ks] = *(const short8*)(Qg + (size_t)(bh * 2048 + q) * 64 + ks * 16 + g2 * 8);

    f32x16 o[2];
#pragma unroll
    for (int dm = 0; dm < 2; ++dm)
#pragma unroll
        for (int r = 0; r < 16; ++r) o[dm][r] = 0.f;
    float mN = -3e38f, lN = 0.f;

    attn_stage(sm, 0, 0, Kg, Vt, bh, w, lane);
    __syncthreads();

    for (int t = 0; t < 32; ++t) {
        const int kv0 = t * 64;
        const char* Kb = sm + (t & 1) * 16384;
        const char* Vb = Kb + 8192;
        if (t + 1 < 32) attn_stage(sm, (t + 1) & 1, kv0 + 64, Kg, Vt, bh, w, lane);

        // S^T = K * Q^T  (exp2-domain scores land directly)
        f32x16 st[2];
#pragma unroll
        for (int cm = 0; cm < 2; ++cm)
#pragma unroll
            for (int r = 0; r < 16; ++r) st[cm][r] = 0.f;
#pragma unroll
        for (int ks = 0; ks < 4; ++ks) {
#pragma unroll
            for (int cm = 0; cm < 2; ++cm) {
                int row = cm * 32 + q31;
                int sl = (2 * ks + g2) ^ (row & 7);
                short8 kf = *(const short8*)(Kb + row * 128 + sl * 16);
                st[cm] = __builtin_amdgcn_mfma_f32_32x32x16_bf16(
                    kf, qf[ks], st[cm], 0, 0, 0);
            }
        }

        // mask + row max   (key = kv0 + cm*32 + (r&3) + 8*(r>>2) + 4*g2)
        float tm = -3e38f;
#pragma unroll
        for (int cm = 0; cm < 2; ++cm) {
#pragma unroll
            for (int rq = 0; rq < 4; ++rq) {
                float4 mk4 = *(const float4*)(mrow + kv0 + cm * 32 + rq * 8 + g2 * 4);
#pragma unroll
                for (int j = 0; j < 4; ++j) {
                    float mk = f4get(mk4, j);
                    float sv = st[cm][rq * 4 + j];
                    sv = (mk >= 0.f) ? sv + mk : mk;
                    st[cm][rq * 4 + j] = sv;
                    tm = fmaxf(tm, sv);
                }
            }
        }
        tm = fmaxf(tm, __shfl_xor(tm, 32));

        // defer-max: only rescale when the running max grew materially
        if (__any(tm > mN + 10.f)) {
            float mnew = fmaxf(mN, tm);
            float ps;
            asm("v_exp_f32 %0, %1" : "=v"(ps) : "v"(mN - mnew));
            mN = mnew;
            lN *= ps;
#pragma unroll
            for (int dm = 0; dm < 2; ++dm)
#pragma unroll
                for (int r = 0; r < 16; ++r) o[dm][r] *= ps;
        }

        // P = 2^(S' - m), row sum
        float ts = 0.f;
#pragma unroll
        for (int cm = 0; cm < 2; ++cm)
#pragma unroll
            for (int r = 0; r < 16; ++r) {
                float p;
                asm("v_exp_f32 %0, %1" : "=v"(p) : "v"(st[cm][r] - mN));
                st[cm][r] = p;
                ts += p;
            }
        ts += __shfl_xor(ts, 32);
        lN += ts;

        // PV: O^T += V^T * P^T ; P^T B-frag via cvt_pk + permlane32_swap
#pragma unroll
        for (int ks = 0; ks < 4; ++ks) {
            const int cm = ks >> 1;
            const int b0 = 8 * (ks & 1);
            unsigned x0, x1, y0, y1;
            asm("v_cvt_pk_bf16_f32 %0, %1, %2" : "=v"(x0) : "v"(st[cm][b0 + 0]), "v"(st[cm][b0 + 1]));
            asm("v_cvt_pk_bf16_f32 %0, %1, %2" : "=v"(x1) : "v"(st[cm][b0 + 2]), "v"(st[cm][b0 + 3]));
            asm("v_cvt_pk_bf16_f32 %0, %1, %2" : "=v"(y0) : "v"(st[cm][b0 + 4]), "v"(st[cm][b0 + 5]));
            asm("v_cvt_pk_bf16_f32 %0, %1, %2" : "=v"(y1) : "v"(st[cm][b0 + 6]), "v"(st[cm][b0 + 7]));
            asm("v_permlane32_swap_b32 %0, %1" : "+v"(x0), "+v"(y0));
            asm("v_permlane32_swap_b32 %0, %1" : "+v"(x1), "+v"(y1));
            union { unsigned u[4]; short8 s; } pb;
            pb.u[0] = x0; pb.u[1] = x1; pb.u[2] = y0; pb.u[3] = y1;
#pragma unroll
            for (int dm = 0; dm < 2; ++dm) {
                int row = dm * 32 + q31;
                int sl = (2 * ks + g2) ^ (row & 7);
                short8 vf = *(const short8*)(Vb + row * 128 + sl * 16);
                o[dm] = __builtin_amdgcn_mfma_f32_32x32x16_bf16(
                    vf, pb.s, o[dm], 0, 0, 0);
            }
        }
        __syncthreads();
    }

    // epilogue: divide by l, write fp32 [B,S,D]
    float inv = 1.f / lN;
#pragma unroll
    for (int dm = 0; dm < 2; ++dm)
#pragma unroll
        for (int rq = 0; rq < 4; ++rq) {
            float4 v;
            v.x = o[dm][rq * 4 + 0] * inv;
            v.y = o[dm][rq * 4 + 1] * inv;
            v.z = o[dm][rq * 4 + 2] * inv;
            v.w = o[dm][rq * 4 + 3] * inv;
            int d = dm * 32 + rq * 8 + g2 * 4;
            *(float4*)(out + (size_t)(bb * 2048 + q) * 1024 + h * 64 + d) = v;
        }
}

extern "C" void kernel_launch(void* const* d_in, const int* in_sizes, int n_in,
                              void* d_out, int out_size, void* d_ws, size_t ws_size,
                              hipStream_t stream) {
    const float* X    = (const float*)d_in[0];
    const float* mask = (const float*)d_in[1];
    const float* Wq   = (const float*)d_in[2];
    const float* bq   = (const float*)d_in[3];
    const float* Wk   = (const float*)d_in[4];
    const float* bk   = (const float*)d_in[5];
    const float* Wv   = (const float*)d_in[6];
    const float* bv   = (const float*)d_in[7];
    float* out = (float*)d_out;

    char* ws = (char*)d_ws;
    unsigned short* Xb = (unsigned short*)(ws + OFF_XB);
    unsigned short* Wc = (unsigned short*)(ws + OFF_WC);
    float*          M2 = (float*)(ws + OFF_M2);
    unsigned short* Qb = (unsigned short*)(ws + OFF_QB);
    unsigned short* Kb = (unsigned short*)(ws + OFF_KB);
    unsigned short* Vb = (unsigned short*)(ws + OFF_VB);
    unsigned short* Vt = (unsigned short*)(ws + OFF_VT);

    convert_kernel<<<11272, 256, 0, stream>>>(X, Wq, Wk, Wv, mask, Xb, Wc, M2);
    qkv_gemm<<<dim3(64, 24), 256, 0, stream>>>(Xb, Wc, bq, bk, bv, Qb, Kb, Vb);
    transpose_v<<<dim3(32, 64), 256, 0, stream>>>(Vb, Vt);
    attn_kernel<<<dim3(16, 64), 256, 0, stream>>>(Qb, Kb, Vt, M2, out);
}